// Round 1
// baseline (442.991 us; speedup 1.0000x reference)
//
#include <hip/hip_runtime.h>
#include <hip/hip_bf16.h>
#include <stdint.h>

#define DIN 4096
#define DOUT 4096

typedef __attribute__((ext_vector_type(8))) short short8;
typedef __attribute__((ext_vector_type(8))) unsigned short ushort8;
typedef __attribute__((ext_vector_type(4))) float f32x4;

__device__ inline unsigned short f2bf(float f) {
    union { float f; unsigned u; } v; v.f = f;
    unsigned r = v.u + 0x7fffu + ((v.u >> 16) & 1u);   // RNE
    return (unsigned short)(r >> 16);
}

// ---- prep 1: x (f32) -> bf16, 8 elems/thread --------------------------------
__global__ void cvt_x_kernel(const float* __restrict__ x, ushort* __restrict__ xb, long n8) {
    long i = (long)blockIdx.x * blockDim.x + threadIdx.x;
    if (i >= n8) return;
    const float4* p = (const float4*)(x + i * 8);
    float4 v0 = p[0], v1 = p[1];
    ushort8 o;
    o[0] = f2bf(v0.x); o[1] = f2bf(v0.y); o[2] = f2bf(v0.z); o[3] = f2bf(v0.w);
    o[4] = f2bf(v1.x); o[5] = f2bf(v1.y); o[6] = f2bf(v1.z); o[7] = f2bf(v1.w);
    *(ushort8*)(xb + i * 8) = o;
}

// ---- prep 2: Wt[e][d] = bf16(base[d][e] + c*mask[d][e])  (64x64 LDS transpose)
__global__ void make_wt_kernel(const float* __restrict__ base, const int* __restrict__ mask,
                               const float* __restrict__ coeff, ushort* __restrict__ wt) {
    __shared__ float tile[64][65];
    const float c = coeff[0];
    const int t = threadIdx.x;                 // 256 threads
    const int bd = blockIdx.x >> 6;            // d-tile
    const int be = blockIdx.x & 63;            // e-tile
    const int d0 = bd * 64, e0 = be * 64;
#pragma unroll
    for (int i = 0; i < 4; ++i) {
        int idx = i * 256 + t;                 // 0..1023 float4-index
        int r = idx >> 4;                      // d-row 0..63
        int c4 = (idx & 15) << 2;              // e-col
        const float4 bv = *(const float4*)(base + (size_t)(d0 + r) * DOUT + e0 + c4);
        const int4  mv = *(const int4*)(mask + (size_t)(d0 + r) * DOUT + e0 + c4);
        tile[r][c4 + 0] = bv.x + c * (float)mv.x;
        tile[r][c4 + 1] = bv.y + c * (float)mv.y;
        tile[r][c4 + 2] = bv.z + c * (float)mv.z;
        tile[r][c4 + 3] = bv.w + c * (float)mv.w;
    }
    __syncthreads();
#pragma unroll
    for (int i = 0; i < 8; ++i) {
        int idx = i * 256 + t;                 // 0..2047 pair index
        int r = idx >> 5;                      // e-row 0..63
        int p = (idx & 31) << 1;               // d-col pair
        ushort2 o;
        o.x = f2bf(tile[p][r]);
        o.y = f2bf(tile[p + 1][r]);
        *(ushort2*)(wt + (size_t)(e0 + r) * DIN + d0 + p) = o;
    }
}

// ---- GEMM: C[M][N] = A[M][K](bf16) * Wt[N][K](bf16), m97 structure ----------
// 128x128 tile, BK=32, 4 waves each computing 64x64, 16x16x32 bf16 MFMA.
__global__ __launch_bounds__(256) void gemm_kernel(const ushort* __restrict__ A,
                                                   const ushort* __restrict__ Bt,
                                                   float* __restrict__ C, int M) {
    __shared__ __align__(16) ushort lA[2][128 * 32];
    __shared__ __align__(16) ushort lB[2][128 * 32];

    const int tid = threadIdx.x;
    const int lane = tid & 63;
    const int wave = tid >> 6;
    const int nbn = DOUT / 128;                // 32
    const int nwg = gridDim.x;

    // XCD-aware swizzle (nwg % 8 == 0 here: 64*32 = 2048)
    int bid = blockIdx.x;
    int cpx = nwg >> 3;
    int s = (bid & 7) * cpx + (bid >> 3);
    const int m0 = (s / nbn) * 128;
    const int n0 = (s % nbn) * 128;

    const int wr = wave >> 1, wc = wave & 1;   // wave -> 64x64 quadrant
    const int fr = lane & 15;                  // fragment row/col
    const int fq = lane >> 4;                  // k-chunk / acc row group

    // staging geometry: tile 8KB = 8 chunks of 1KB; wave w stages chunks w and w+4
    const int srow = (lane >> 2);              // +chunk*16
    const int skb = (lane & 3) * 16;           // byte offset within 64B row

    auto stage = [&](int buf, int t) {
        const int k0 = t * 32;
#pragma unroll
        for (int q = 0; q < 2; ++q) {
            int chunk = q * 4 + wave;
            int row = chunk * 16 + srow;
            const char* gA = (const char*)(A + (size_t)(m0 + row) * DIN + k0) + skb;
            __builtin_amdgcn_global_load_lds(
                (const __attribute__((address_space(1))) void*)gA,
                (__attribute__((address_space(3))) void*)&lA[buf][chunk * 512], 16, 0, 0);
        }
#pragma unroll
        for (int q = 0; q < 2; ++q) {
            int chunk = q * 4 + wave;
            int row = chunk * 16 + srow;
            const char* gB = (const char*)(Bt + (size_t)(n0 + row) * DIN + k0) + skb;
            __builtin_amdgcn_global_load_lds(
                (const __attribute__((address_space(1))) void*)gB,
                (__attribute__((address_space(3))) void*)&lB[buf][chunk * 512], 16, 0, 0);
        }
    };

    f32x4 acc[4][4] = {};

    stage(0, 0);
    int cur = 0;
    const int nt = DIN / 32;                   // 128
    for (int t = 0; t < nt; ++t) {
        __syncthreads();                       // buf[cur] staged; prev reads done
        if (t + 1 < nt) stage(cur ^ 1, t + 1); // prefetch next while computing
        short8 af[4], bf_[4];
#pragma unroll
        for (int m = 0; m < 4; ++m)
            af[m] = *(const short8*)&lA[cur][(wr * 64 + m * 16 + fr) * 32 + fq * 8];
#pragma unroll
        for (int n = 0; n < 4; ++n)
            bf_[n] = *(const short8*)&lB[cur][(wc * 64 + n * 16 + fr) * 32 + fq * 8];
#pragma unroll
        for (int m = 0; m < 4; ++m)
#pragma unroll
            for (int n = 0; n < 4; ++n)
                acc[m][n] = __builtin_amdgcn_mfma_f32_16x16x32_bf16(af[m], bf_[n], acc[m][n], 0, 0, 0);
        cur ^= 1;
    }

    // epilogue: C/D layout col = lane&15, row = (lane>>4)*4 + j  [m89-verified]
#pragma unroll
    for (int m = 0; m < 4; ++m) {
        int grow = m0 + wr * 64 + m * 16 + fq * 4;
#pragma unroll
        for (int n = 0; n < 4; ++n) {
            int gcol = n0 + wc * 64 + n * 16 + fr;
#pragma unroll
            for (int j = 0; j < 4; ++j)
                C[(size_t)(grow + j) * DOUT + gcol] = acc[m][n][j];
        }
    }
}

extern "C" void kernel_launch(void* const* d_in, const int* in_sizes, int n_in,
                              void* d_out, int out_size, void* d_ws, size_t ws_size,
                              hipStream_t stream) {
    const float* x = (const float*)d_in[0];
    const float* base = (const float*)d_in[1];
    const float* coeff = (const float*)d_in[2];
    const int* mask = (const int*)d_in[3];
    float* out = (float*)d_out;

    const int M = in_sizes[0] / DIN;           // 8192
    ushort* xb = (ushort*)d_ws;                // M*DIN bf16  (64 MB)
    ushort* wt = xb + (size_t)M * DIN;         // DOUT*DIN bf16 (32 MB)

    long n8 = (long)M * DIN / 8;
    cvt_x_kernel<<<(int)((n8 + 255) / 256), 256, 0, stream>>>(x, xb, n8);
    make_wt_kernel<<<(DIN / 64) * (DOUT / 64), 256, 0, stream>>>(base, mask, coeff, wt);

    const int nwg = (M / 128) * (DOUT / 128);  // 2048
    gemm_kernel<<<nwg, 256, 0, stream>>>(xb, wt, out, M);
}

// Round 2
// 323.501 us; speedup vs baseline: 1.3694x; 1.3694x over previous
//
#include <hip/hip_runtime.h>
#include <hip/hip_bf16.h>
#include <stdint.h>

#define DIN 4096
#define DOUT 4096
#define BK 64
#define NT (DIN / BK)   // 64 K-tiles

typedef __attribute__((ext_vector_type(8))) short short8;
typedef __attribute__((ext_vector_type(8))) unsigned short ushort8;
typedef __attribute__((ext_vector_type(4))) float f32x4;

__device__ inline unsigned short f2bf(float f) {
    union { float f; unsigned u; } v; v.f = f;
    unsigned r = v.u + 0x7fffu + ((v.u >> 16) & 1u);   // RNE
    return (unsigned short)(r >> 16);
}

// ---- prep 1: x (f32) -> bf16, 8 elems/thread --------------------------------
__global__ void cvt_x_kernel(const float* __restrict__ x, ushort* __restrict__ xb, long n8) {
    long i = (long)blockIdx.x * blockDim.x + threadIdx.x;
    if (i >= n8) return;
    const float4* p = (const float4*)(x + i * 8);
    float4 v0 = p[0], v1 = p[1];
    ushort8 o;
    o[0] = f2bf(v0.x); o[1] = f2bf(v0.y); o[2] = f2bf(v0.z); o[3] = f2bf(v0.w);
    o[4] = f2bf(v1.x); o[5] = f2bf(v1.y); o[6] = f2bf(v1.z); o[7] = f2bf(v1.w);
    *(ushort8*)(xb + i * 8) = o;
}

// ---- prep 2: Wt[e][d] = bf16(base[d][e] + c*mask[d][e])  (64x64 LDS transpose)
__global__ void make_wt_kernel(const float* __restrict__ base, const int* __restrict__ mask,
                               const float* __restrict__ coeff, ushort* __restrict__ wt) {
    __shared__ float tile[64][65];
    const float c = coeff[0];
    const int t = threadIdx.x;                 // 256 threads
    const int bd = blockIdx.x >> 6;            // d-tile
    const int be = blockIdx.x & 63;            // e-tile
    const int d0 = bd * 64, e0 = be * 64;
#pragma unroll
    for (int i = 0; i < 4; ++i) {
        int idx = i * 256 + t;                 // 0..1023 float4-index
        int r = idx >> 4;                      // d-row 0..63
        int c4 = (idx & 15) << 2;              // e-col
        const float4 bv = *(const float4*)(base + (size_t)(d0 + r) * DOUT + e0 + c4);
        const int4  mv = *(const int4*)(mask + (size_t)(d0 + r) * DOUT + e0 + c4);
        tile[r][c4 + 0] = bv.x + c * (float)mv.x;
        tile[r][c4 + 1] = bv.y + c * (float)mv.y;
        tile[r][c4 + 2] = bv.z + c * (float)mv.z;
        tile[r][c4 + 3] = bv.w + c * (float)mv.w;
    }
    __syncthreads();
#pragma unroll
    for (int i = 0; i < 8; ++i) {
        int idx = i * 256 + t;                 // 0..2047 pair index
        int r = idx >> 5;                      // e-row 0..63
        int p = (idx & 31) << 1;               // d-col pair
        ushort2 o;
        o.x = f2bf(tile[p][r]);
        o.y = f2bf(tile[p + 1][r]);
        *(ushort2*)(wt + (size_t)(e0 + r) * DIN + d0 + p) = o;
    }
}

// ---- GEMM: 256x256 tile, BK=64, 8-phase schedule (T2+T3+T4+T5) --------------
// C[M][N] = A[M][K](bf16) * Bt[N][K](bf16), both row-major with K contiguous.

#define MFMA(d, va, vb) d = __builtin_amdgcn_mfma_f32_16x16x32_bf16(va, vb, d, 0, 0, 0)

#define PHASE_CORE(AOFF) \
    __builtin_amdgcn_s_barrier(); \
    asm volatile("s_waitcnt lgkmcnt(0)" ::: "memory"); \
    __builtin_amdgcn_sched_barrier(0); \
    __builtin_amdgcn_s_setprio(1); \
    MFMA(acc[AOFF+0][0],a0,b0); MFMA(acc[AOFF+0][1],a0,b1); MFMA(acc[AOFF+0][2],a0,b2); MFMA(acc[AOFF+0][3],a0,b3); \
    MFMA(acc[AOFF+1][0],a1,b0); MFMA(acc[AOFF+1][1],a1,b1); MFMA(acc[AOFF+1][2],a1,b2); MFMA(acc[AOFF+1][3],a1,b3); \
    MFMA(acc[AOFF+2][0],a2,b0); MFMA(acc[AOFF+2][1],a2,b1); MFMA(acc[AOFF+2][2],a2,b2); MFMA(acc[AOFF+2][3],a2,b3); \
    MFMA(acc[AOFF+3][0],a3,b0); MFMA(acc[AOFF+3][1],a3,b1); MFMA(acc[AOFF+3][2],a3,b2); MFMA(acc[AOFF+3][3],a3,b3); \
    __builtin_amdgcn_s_setprio(0);

// K-tile: 4 phases (oh,kk); stage schedule:
//  ph(0,kk0): stage A.kk1(U+1) -> other buf   ph(1,kk0): stage B.kk1(U+1)
//  ph(0,kk1): stage A.kk0(U+2) -> this buf    ph(1,kk1): stage B.kk0(U+2)
// boundary: vmcnt(4) steady (leaves next-next kk0 in flight); vmcnt(0) at tail.
#define KTILE(BUFI, U, G1, G2, NEXT) \
    { \
        const ushort* LA0 = lA[BUFI][0]; const ushort* LA1 = lA[BUFI][1]; \
        const ushort* LB0 = lB[BUFI][0]; const ushort* LB1 = lB[BUFI][1]; \
        short8 a0,a1,a2,a3,b0,b1,b2,b3; \
        a0=rdA(LA0,0,0); a1=rdA(LA0,0,1); a2=rdA(LA0,0,2); a3=rdA(LA0,0,3); \
        b0=rdB(LB0,0); b1=rdB(LB0,1); b2=rdB(LB0,2); b3=rdB(LB0,3); \
        if (G1) stage(lA[1-(BUFI)][1], A, m0, (U)+1, 1); \
        PHASE_CORE(0) \
        __builtin_amdgcn_s_barrier(); \
        a0=rdA(LA0,1,0); a1=rdA(LA0,1,1); a2=rdA(LA0,1,2); a3=rdA(LA0,1,3); \
        if (G1) stage(lB[1-(BUFI)][1], Bt, n0, (U)+1, 1); \
        PHASE_CORE(4) \
        __builtin_amdgcn_s_barrier(); \
        a0=rdA(LA1,0,0); a1=rdA(LA1,0,1); a2=rdA(LA1,0,2); a3=rdA(LA1,0,3); \
        b0=rdB(LB1,0); b1=rdB(LB1,1); b2=rdB(LB1,2); b3=rdB(LB1,3); \
        if (G2) stage(lA[BUFI][0], A, m0, (U)+2, 0); \
        PHASE_CORE(0) \
        __builtin_amdgcn_s_barrier(); \
        a0=rdA(LA1,1,0); a1=rdA(LA1,1,1); a2=rdA(LA1,1,2); a3=rdA(LA1,1,3); \
        if (G2) stage(lB[BUFI][0], Bt, n0, (U)+2, 0); \
        PHASE_CORE(4) \
        if (G2)        { asm volatile("s_waitcnt vmcnt(4)" ::: "memory"); } \
        else if (NEXT) { asm volatile("s_waitcnt vmcnt(0)" ::: "memory"); } \
        __builtin_amdgcn_s_barrier(); \
        __builtin_amdgcn_sched_barrier(0); \
    }

__global__ __launch_bounds__(512, 2) void gemm_kernel(const ushort* __restrict__ A,
                                                      const ushort* __restrict__ Bt,
                                                      float* __restrict__ C) {
    // [buf][kk][256 rows * 32 cols bf16] per matrix; 64-B rows; 128 KiB total
    __shared__ __align__(16) ushort lA[2][2][256 * 32];
    __shared__ __align__(16) ushort lB[2][2][256 * 32];

    const int tid = threadIdx.x;
    const int lane = tid & 63;
    const int wave = tid >> 6;

    const int nbn = DOUT / 256;               // 16
    const int nwg = gridDim.x;                // 512 (multiple of 8)
    int bid = blockIdx.x;
    int cpx = nwg >> 3;
    int s = (bid & 7) * cpx + (bid >> 3);     // XCD-contiguous chunks
    const int m0 = (s / nbn) * 256;
    const int n0 = (s % nbn) * 256;

    const int wr = wave >> 2;                 // 0..1  (M half)
    const int wc = wave & 3;                  // 0..3  (N quarter)
    const int fr = lane & 15;
    const int fq = lane >> 4;                 // 0..3

    const int st_r = tid >> 2;                // 0..127
    const int st_c = (tid & 3) << 4;          // byte col 0/16/32/48

    // stage one K-split half (256 rows x 32 bf16): linear LDS dest,
    // inverse-swizzled global source (rule #21; swizzle s(row)=((row>>1)&3)<<4)
    auto stage = [&](ushort* region, const ushort* gBase, int rowBase, int t, int kk) {
#pragma unroll
        for (int j = 0; j < 2; ++j) {
            int row = j * 128 + st_r;
            int sc = st_c ^ (((row >> 1) & 3) << 4);
            const char* g = (const char*)(gBase + (size_t)(rowBase + row) * DIN + t * BK + kk * 32) + sc;
            char* d = (char*)region + row * 64 + st_c;
            __builtin_amdgcn_global_load_lds(
                (const __attribute__((address_space(1))) void*)g,
                (__attribute__((address_space(3))) void*)d, 16, 0, 0);
        }
    };

    auto rdA = [&](const ushort* region, int oh, int m) -> short8 {
        int row = wr * 128 + oh * 64 + m * 16 + fr;
        int cb = (fq << 4) ^ (((row >> 1) & 3) << 4);
        return *(const short8*)((const char*)region + row * 64 + cb);
    };
    auto rdB = [&](const ushort* region, int n) -> short8 {
        int row = wc * 64 + n * 16 + fr;
        int cb = (fq << 4) ^ (((row >> 1) & 3) << 4);
        return *(const short8*)((const char*)region + row * 64 + cb);
    };

    f32x4 acc[8][4] = {};

    // prologue: tile0 (both halves) then tile1.kk0 -> 12 loads/wave in flight
    stage(lA[0][0], A, m0, 0, 0);
    stage(lB[0][0], Bt, n0, 0, 0);
    stage(lA[0][1], A, m0, 0, 1);
    stage(lB[0][1], Bt, n0, 0, 1);
    stage(lA[1][0], A, m0, 1, 0);
    stage(lB[1][0], Bt, n0, 1, 0);
    asm volatile("s_waitcnt vmcnt(4)" ::: "memory");   // tile0's 8 loads landed
    __builtin_amdgcn_s_barrier();
    __builtin_amdgcn_sched_barrier(0);

    for (int u = 0; u < NT; u += 2) {
        KTILE(0, u, 1, (u + 2 < NT), 1)
        KTILE(1, u + 1, (u + 2 < NT), (u + 3 < NT), (u + 2 < NT))
    }

    // epilogue: C/D frag layout col=fr, row=fq*4+j
#pragma unroll
    for (int a = 0; a < 8; ++a) {
        int grow = m0 + wr * 128 + (a >> 2) * 64 + (a & 3) * 16 + fq * 4;
#pragma unroll
        for (int n = 0; n < 4; ++n) {
            int gcol = n0 + wc * 64 + n * 16 + fr;
#pragma unroll
            for (int j = 0; j < 4; ++j)
                C[(size_t)(grow + j) * DOUT + gcol] = acc[a][n][j];
        }
    }
}

extern "C" void kernel_launch(void* const* d_in, const int* in_sizes, int n_in,
                              void* d_out, int out_size, void* d_ws, size_t ws_size,
                              hipStream_t stream) {
    const float* x = (const float*)d_in[0];
    const float* base = (const float*)d_in[1];
    const float* coeff = (const float*)d_in[2];
    const int* mask = (const int*)d_in[3];
    float* out = (float*)d_out;

    const int M = in_sizes[0] / DIN;           // 8192
    ushort* xb = (ushort*)d_ws;                // M*DIN bf16  (64 MB)
    ushort* wt = xb + (size_t)M * DIN;         // DOUT*DIN bf16 (32 MB)

    long n8 = (long)M * DIN / 8;
    cvt_x_kernel<<<(int)((n8 + 255) / 256), 256, 0, stream>>>(x, xb, n8);
    make_wt_kernel<<<(DIN / 64) * (DOUT / 64), 256, 0, stream>>>(base, mask, coeff, wt);

    const int nwg = (M / 256) * (DOUT / 256);  // 512
    gemm_kernel<<<nwg, 512, 0, stream>>>(xb, wt, out);
}